// Round 6
// baseline (758.896 us; speedup 1.0000x reference)
//
#include <hip/hip_runtime.h>
#include <cstddef>
#include <cstdint>

// ---------------------------------------------------------------------------
// CornerPosFeatExtractor fused kernel, round 6.
// NEW: phase C (proj, 4.65 GMAC) runs on MFMA via split-bf16 (hi+lo, 3 passes,
// fp32 accumulate; ~1e-5 abs error). Phase E (conv) / F (addLN) byte-identical
// to the audited round-5 kernel. Phase D remapped to MFMA fragment ownership
// but writes the SAME swizzled fp LDS layout phase E expects.
//
// Pipeline:
//   k_init      : zero aligned output + write mask
//   k_wtrans    : proj_w -> pwA_hi/lo (per-lane MFMA A-fragments, bf16),
//                 conv_w -> cwT[e][k][d] fp32                    (ws, 1.25MB)
//   k_transpose : feat NCHW -> NHWC tfeat, float4 both sides     (ws, 134MB)
//   k_main_fast : sample -> bf16-split cf -> MFMA proj -> +posLN(analytic)
//                 -> fp32 conv (stream-bound) -> addLN -> store
//
// MFMA mapping (16x16x32 bf16): A row = l&15, k = (l>>4)*8+j (pre-packed in
// ws); B col = l&15, same k (cf LDS, chunk XOR p&7 -> 2-way = free);
// D row = (l>>4)*4+reg, col = l&15 [guide m89-verified].
// cf LDS: hi/lo ushort planes [32 p][256 ch], physical chunk = chunk ^ (p&7).
// ---------------------------------------------------------------------------

#define BB    8
#define CIN_  256
#define DDIM  256
#define HH    128
#define WW    128
#define HW    (HH*WW)
#define MAXR  64
#define MAXC  64
#define CELLS 8
#define PTS   32   // 4*CELLS

#define PWA_USHORTS (256*256)        // 65536 per plane (hi / lo)
#define CWT_FLOATS  (256*256*4)      // 262144
#define WS_WBYTES   ((size_t)PWA_USHORTS*2*sizeof(unsigned short) + (size_t)CWT_FLOATS*sizeof(float))
#define TF_FLOATS   ((size_t)BB*CIN_*HW)

typedef __attribute__((ext_vector_type(8))) short bf16x8;
typedef __attribute__((ext_vector_type(4))) float f32x4;

__device__ __forceinline__ unsigned short f2bf(float x) {
  unsigned u = __float_as_uint(x);
  return (unsigned short)((u + 0x7FFFu + ((u >> 16) & 1u)) >> 16);  // RNE
}
__device__ __forceinline__ float bf2f(unsigned short b) {
  return __uint_as_float(((unsigned)b) << 16);
}

// num_rows/num_cols are np.int64 in the reference; harness may hand us int32
// or raw int64. Counts are all >=24, so word[1]==0 iff int64 little-endian.
__device__ __forceinline__ int load_count(const int* __restrict__ p, int idx) {
  return (p[1] == 0) ? p[2 * idx] : p[idx];
}

// ---------------- init: zero aligned output + write mask -------------------
__global__ void k_init(float* __restrict__ out,
                       const int* __restrict__ nr, const int* __restrict__ nc) {
  const size_t NAL4 = (size_t)BB * DDIM * MAXR * MAXC / 4;  // float4 count
  size_t i = (size_t)blockIdx.x * blockDim.x + threadIdx.x;
  if (i < NAL4) {
    ((float4*)out)[i] = make_float4(0.f, 0.f, 0.f, 0.f);
  } else {
    size_t mi = i - NAL4;
    const size_t NM = (size_t)BB * MAXR * MAXC;
    if (mi < NM) {
      int b = (int)(mi / (MAXR * MAXC));
      int rc = (int)(mi % (MAXR * MAXC));
      int r = rc / MAXC, c = rc % MAXC;
      int R = load_count(nr, b), C = load_count(nc, b);
      out[(size_t)BB * DDIM * MAXR * MAXC + mi] = (r < R && c < C) ? 1.f : 0.f;
    }
  }
}

// ---------------- weight prep into workspace -------------------------------
// pwA_{hi,lo}[((dt*8 + kc)*64 + lane)*8 + j] = bf16 split of
//     proj_w[dt*16 + (lane&15)][kc*32 + (lane>>4)*8 + j]   (MFMA A fragment)
// cwT[(e*4+kk)*256 + d] = conv_w[d*1024 + e*4 + kk]         (fp32, phase E)
__global__ void k_wtrans(const float* __restrict__ pw, const float* __restrict__ cw,
                         unsigned short* __restrict__ pwA_hi,
                         unsigned short* __restrict__ pwA_lo,
                         float* __restrict__ cwT) {
  int i = blockIdx.x * 256 + threadIdx.x;
  if (i < PWA_USHORTS) {
    int dt = i >> 12, kc = (i >> 9) & 7, ln = (i >> 3) & 63, j = i & 7;
    int d = dt * 16 + (ln & 15);
    int k = kc * 32 + ((ln >> 4) << 3) + j;
    float v = pw[d * 256 + k];
    unsigned short h = f2bf(v);
    pwA_hi[i] = h;
    pwA_lo[i] = f2bf(v - bf2f(h));
  } else {
    int jx = i - PWA_USHORTS;
    if (jx < CWT_FLOATS) {
      int e = jx >> 10, kk = (jx >> 8) & 3, d = jx & 255;
      cwT[jx] = cw[d * 1024 + e * 4 + kk];
    }
  }
}

// ---------------- transpose feat NCHW -> NHWC (float4 both sides) ----------
__global__ __launch_bounds__(256)
void k_transpose(const float* __restrict__ feat, float* __restrict__ tfeat) {
  __shared__ float tile[32][33];
  const int pix0 = blockIdx.x * 32;       // over H*W (16384)
  const int ch0  = blockIdx.y * 32;       // over CIN (256)
  const int b    = blockIdx.z;
  const int t  = threadIdx.x;             // 0..255
  const int tx = t & 7;                   // quad index
  const int ty = t >> 3;                  // 0..31
  const float4* fb4 = (const float4*)(feat + (size_t)b * CIN_ * HW);
  float4*       tb4 = (float4*)(tfeat + (size_t)b * CIN_ * HW);

  float4 v = fb4[((size_t)(ch0 + ty) * HW + pix0) / 4 + tx];
  tile[ty][4 * tx + 0] = v.x;
  tile[ty][4 * tx + 1] = v.y;
  tile[ty][4 * tx + 2] = v.z;
  tile[ty][4 * tx + 3] = v.w;
  __syncthreads();

  float4 o;
  o.x = tile[4 * tx + 0][ty];
  o.y = tile[4 * tx + 1][ty];
  o.z = tile[4 * tx + 2][ty];
  o.w = tile[4 * tx + 3][ty];
  tb4[((size_t)(pix0 + ty) * CIN_ + ch0) / 4 + tx] = o;
}

// ---------------- fused main kernel (MFMA proj) ----------------------------
template<bool NHWC>
__global__ __launch_bounds__(256)
void k_main_fast(const float* __restrict__ feat,   // NHWC ? tfeat : original
                 const float* __restrict__ boxes,
                 const unsigned short* __restrict__ pwA_hi,
                 const unsigned short* __restrict__ pwA_lo,
                 const float* __restrict__ proj_b,
                 const float* __restrict__ bbox_w, const float* __restrict__ bbox_b,
                 const float* __restrict__ bboxln_w, const float* __restrict__ bboxln_b,
                 const float* __restrict__ cwT,    // [e][k][d] fp32
                 const float* __restrict__ conv_b,
                 const float* __restrict__ addln_w, const float* __restrict__ addln_b,
                 const int* __restrict__ nr, const int* __restrict__ nc,
                 float* __restrict__ out) {
  const int b  = blockIdx.z;
  const int r  = blockIdx.y;
  const int c0 = blockIdx.x * CELLS;
  const int R = load_count(nr, b);
  const int C = load_count(nc, b);
  if (r >= R || c0 >= C) return;

  const int t    = threadIdx.x;
  const int lane = t & 63;
  const int wave = t >> 6;
  const int lq   = lane & 15;
  const int ph   = lane >> 4;
  const int wbase = 16 * wave + lq;      // phase E/F: d = 4*wbase + i

  // s_buf: phases B/C = cf bf16 hi/lo planes (16KB+16KB); phases D/E = fp fp32
  __shared__ float s_buf[PTS * CIN_];                       // 32 KB, aliased
  __shared__ float s_w00[PTS], s_w01[PTS], s_w10[PTS], s_w11[PTS];
  __shared__ int   s_o00[PTS], s_o01[PTS], s_o10[PTS], s_o11[PTS];
  __shared__ float s_gx[PTS], s_gy[PTS], s_pm[PTS], s_pi[PTS];
  __shared__ float s_red[4][9];
  __shared__ float s_stat[9];
  __shared__ float s_ps[2][CELLS][4];    // addLN partials [stat][cell][wave]
  __shared__ float s_mv[CELLS][2];       // addLN mean/inv per cell

  // ---- phase 0: moments of (bbox_w, bbox_b) for analytic pos-LN ----
  {
    int d = t;
    float w0 = bbox_w[2 * d], w1 = bbox_w[2 * d + 1], bv = bbox_b[d];
    float v[9] = {w0, w1, bv, w0 * w0, w1 * w1, bv * bv, w0 * w1, w0 * bv, w1 * bv};
#pragma unroll
    for (int m = 32; m >= 1; m >>= 1) {
#pragma unroll
      for (int q = 0; q < 9; q++) v[q] += __shfl_xor(v[q], m);
    }
    if (lane == 0) {
#pragma unroll
      for (int q = 0; q < 9; q++) s_red[wave][q] = v[q];
    }
  }
  __syncthreads();
  if (t < 9) s_stat[t] = s_red[0][t] + s_red[1][t] + s_red[2][t] + s_red[3][t];
  __syncthreads();

  // ---- phase A: per-point sampling params + pos-LN mean/inv ----
  if (t < PTS) {
    int p = t;
    int cl = p >> 2, k = p & 3;
    int c = c0 + cl;                       // < 64 always: memory-safe
    const float* bp = boxes + ((((size_t)b * MAXR + r) * MAXC + c) * 4 + k) * 2;
    float bx = bp[0], by = bp[1];
    float px = bx * 0.25f - 0.5f;
    float py = by * 0.25f - 0.5f;
    float x0f = floorf(px), y0f = floorf(py);
    float wx1 = px - x0f, wx0 = 1.f - wx1;
    float wy1 = py - y0f, wy0 = 1.f - wy1;
    int x0 = (int)x0f, y0 = (int)y0f;
    int x1 = x0 + 1, y1 = y0 + 1;
    bool vx0 = (x0 >= 0) & (x0 < WW), vx1 = (x1 >= 0) & (x1 < WW);
    bool vy0 = (y0 >= 0) & (y0 < HH), vy1 = (y1 >= 0) & (y1 < HH);
    int x0c = min(max(x0, 0), WW - 1), x1c = min(max(x1, 0), WW - 1);
    int y0c = min(max(y0, 0), HH - 1), y1c = min(max(y1, 0), HH - 1);
    s_w00[p] = wx0 * wy0 * ((vx0 && vy0) ? 1.f : 0.f);
    s_w01[p] = wx1 * wy0 * ((vx1 && vy0) ? 1.f : 0.f);
    s_w10[p] = wx0 * wy1 * ((vx0 && vy1) ? 1.f : 0.f);
    s_w11[p] = wx1 * wy1 * ((vx1 && vy1) ? 1.f : 0.f);
    if (NHWC) {
      int base = b * HW;
      s_o00[p] = (base + y0c * WW + x0c) << 8;   // *CIN channels
      s_o01[p] = (base + y0c * WW + x1c) << 8;
      s_o10[p] = (base + y1c * WW + x0c) << 8;
      s_o11[p] = (base + y1c * WW + x1c) << 8;
    } else {
      int base = b * CIN_ * HW;
      s_o00[p] = base + y0c * WW + x0c;
      s_o01[p] = base + y0c * WW + x1c;
      s_o10[p] = base + y1c * WW + x0c;
      s_o11[p] = base + y1c * WW + x1c;
    }
    float gx = bx * (1.f / 256.f) - 1.f;
    float gy = by * (1.f / 256.f) - 1.f;
    s_gx[p] = gx; s_gy[p] = gy;
    const float inv256 = 1.f / 256.f;
    float mean = (s_stat[0] * gx + s_stat[1] * gy + s_stat[2]) * inv256;
    float e2 = (s_stat[3] * gx * gx + s_stat[4] * gy * gy + s_stat[5]
                + 2.f * (s_stat[6] * gx * gy + s_stat[7] * gx + s_stat[8] * gy)) * inv256;
    float var = e2 - mean * mean;
    s_pm[p] = mean;
    s_pi[p] = rsqrtf(var + 1e-5f);
  }
  __syncthreads();

  // ---- phase B: bilinear-sample -> cf bf16 hi/lo planes --------------------
  // cf_{hi,lo}[p][256 ch], physical chunk(8ch) = logical chunk ^ (p&7).
  {
    unsigned short* cfh = (unsigned short*)s_buf;
    unsigned short* cfl = cfh + PTS * CIN_;
    if (NHWC) {
      const float4* f4 = (const float4*)feat;
#pragma unroll
      for (int j = 0; j < 8; j++) {
        int p = wave * 8 + j;
        float w00 = s_w00[p], w01 = s_w01[p], w10 = s_w10[p], w11 = s_w11[p];
        float4 v00 = f4[(s_o00[p] >> 2) + lane];
        float4 v01 = f4[(s_o01[p] >> 2) + lane];
        float4 v10 = f4[(s_o10[p] >> 2) + lane];
        float4 v11 = f4[(s_o11[p] >> 2) + lane];
        float4 a;
        a.x = w00 * v00.x + w01 * v01.x + w10 * v10.x + w11 * v11.x;
        a.y = w00 * v00.y + w01 * v01.y + w10 * v10.y + w11 * v11.y;
        a.z = w00 * v00.z + w01 * v01.z + w10 * v10.z + w11 * v11.z;
        a.w = w00 * v00.w + w01 * v01.w + w10 * v10.w + w11 * v11.w;
        unsigned short h0 = f2bf(a.x), h1 = f2bf(a.y), h2 = f2bf(a.z), h3 = f2bf(a.w);
        unsigned long long hp = (unsigned long long)h0 | ((unsigned long long)h1 << 16)
                              | ((unsigned long long)h2 << 32) | ((unsigned long long)h3 << 48);
        unsigned short l0 = f2bf(a.x - bf2f(h0)), l1 = f2bf(a.y - bf2f(h1));
        unsigned short l2 = f2bf(a.z - bf2f(h2)), l3 = f2bf(a.w - bf2f(h3));
        unsigned long long lp = (unsigned long long)l0 | ((unsigned long long)l1 << 16)
                              | ((unsigned long long)l2 << 32) | ((unsigned long long)l3 << 48);
        // channels 4*lane..+3: chunk = lane>>1, half = lane&1
        int base = p * 256 + ((((lane >> 1) ^ (p & 7)) << 3) + ((lane & 1) << 2));
        *(unsigned long long*)(cfh + base) = hp;
        *(unsigned long long*)(cfl + base) = lp;
      }
    } else {
#pragma unroll
      for (int j = 0; j < 8; j++) {
        int p = wave * 8 + j;
        float w00 = s_w00[p], w01 = s_w01[p], w10 = s_w10[p], w11 = s_w11[p];
        int o00 = s_o00[p], o01 = s_o01[p], o10 = s_o10[p], o11 = s_o11[p];
#pragma unroll
        for (int q = 0; q < 4; q++) {
          int ch = lane + 64 * q;
          int cho = ch * HW;
          float v = w00 * feat[o00 + cho] + w01 * feat[o01 + cho]
                  + w10 * feat[o10 + cho] + w11 * feat[o11 + cho];
          unsigned short h = f2bf(v);
          int bidx = p * 256 + ((((ch >> 3) ^ (p & 7)) << 3) + (ch & 7));
          cfh[bidx] = h;
          cfl[bidx] = f2bf(v - bf2f(h));
        }
      }
    }
  }
  __syncthreads();

  // ---- phase C: proj via MFMA 16x16x32 bf16, split hi/lo (3 passes) -------
  // Wave owns d in [64w,64w+64): 4 d-tiles x 2 p-tiles x 8 k-chunks.
  f32x4 pacc[4][2];
#pragma unroll
  for (int dt = 0; dt < 4; dt++)
#pragma unroll
    for (int pt = 0; pt < 2; pt++)
      pacc[dt][pt] = (f32x4){0.f, 0.f, 0.f, 0.f};

  {
    const bf16x8* gAh = (const bf16x8*)pwA_hi;
    const bf16x8* gAl = (const bf16x8*)pwA_lo;
    const unsigned short* cfh = (const unsigned short*)s_buf;
    const unsigned short* cfl = cfh + PTS * CIN_;
#pragma unroll 2
    for (int kc = 0; kc < 8; kc++) {
      bf16x8 ah[4], al[4];
#pragma unroll
      for (int dt = 0; dt < 4; dt++) {
        int gt = wave * 4 + dt;            // global d-tile
        ah[dt] = gAh[(gt * 8 + kc) * 64 + lane];
        al[dt] = gAl[(gt * 8 + kc) * 64 + lane];
      }
#pragma unroll
      for (int pt = 0; pt < 2; pt++) {
        int p = pt * 16 + (lane & 15);
        int ch = (kc * 4 + (lane >> 4)) ^ (p & 7);
        bf16x8 bh = *(const bf16x8*)(cfh + p * 256 + ch * 8);
        bf16x8 bl = *(const bf16x8*)(cfl + p * 256 + ch * 8);
#pragma unroll
        for (int dt = 0; dt < 4; dt++) {
          pacc[dt][pt] = __builtin_amdgcn_mfma_f32_16x16x32_bf16(ah[dt], bh, pacc[dt][pt], 0, 0, 0);
          pacc[dt][pt] = __builtin_amdgcn_mfma_f32_16x16x32_bf16(ah[dt], bl, pacc[dt][pt], 0, 0, 0);
          pacc[dt][pt] = __builtin_amdgcn_mfma_f32_16x16x32_bf16(al[dt], bh, pacc[dt][pt], 0, 0, 0);
        }
      }
    }
  }
  __syncthreads();   // cf dead; s_buf becomes fp fp32 plane

  // ---- phase D: fp[e][cell-slot][corner] = proj + proj_b + posLN ----------
  // D fragment: d = 64w + dt*16 + (l>>4)*4 + reg, p = pt*16 + (l&15).
  // Same swizzled scalar layout phase E reads: addr = e*32 + (cell^sw)*4 + corner.
  {
    const int q   = lane >> 4;
    const int col = lane & 15;
#pragma unroll
    for (int dt = 0; dt < 4; dt++) {
#pragma unroll
      for (int reg = 0; reg < 4; reg++) {
        int d = wave * 64 + dt * 16 + q * 4 + reg;
        float bw0 = bbox_w[2 * d], bw1 = bbox_w[2 * d + 1], bbv = bbox_b[d];
        float lnw = bboxln_w[d], lnb = bboxln_b[d], pbv = proj_b[d];
        int swd = (d >> 2) & 7;
#pragma unroll
        for (int pt = 0; pt < 2; pt++) {
          int p = pt * 16 + col;
          float tpos = fmaf(bw0, s_gx[p], fmaf(bw1, s_gy[p], bbv));
          float pos = fmaf((tpos - s_pm[p]) * s_pi[p], lnw, lnb);
          float val = pacc[dt][pt][reg] + pbv + pos;
          int cell = p >> 2, corner = p & 3;
          s_buf[d * 32 + ((cell ^ swd) << 2) + corner] = val;
        }
      }
    }
  }
  __syncthreads();

  // ---- phase E: conv (fp32, unchanged audited path) -----------------------
  float cacc[4][2];
#pragma unroll
  for (int i = 0; i < 4; i++) { cacc[i][0] = 0.f; cacc[i][1] = 0.f; }

  const float4* cwT4 = (const float4*)cwT;
  const float4* fp4  = (const float4*)s_buf;
#pragma unroll 2
  for (int e = 0; e < 256; e++) {
    float wkf[16];
#pragma unroll
    for (int k = 0; k < 4; k++)
      *reinterpret_cast<float4*>(&wkf[4 * k]) = cwT4[(e * 4 + k) * 64 + wbase];
    int sw = (e >> 2) & 7;
#pragma unroll
    for (int jj = 0; jj < 2; jj++) {
      float4 fv = fp4[e * 8 + ((2 * ph + jj) ^ sw)];
#pragma unroll
      for (int i = 0; i < 4; i++) {
        cacc[i][jj] = fmaf(wkf[i],      fv.x, cacc[i][jj]);
        cacc[i][jj] = fmaf(wkf[4 + i],  fv.y, cacc[i][jj]);
        cacc[i][jj] = fmaf(wkf[8 + i],  fv.z, cacc[i][jj]);
        cacc[i][jj] = fmaf(wkf[12 + i], fv.w, cacc[i][jj]);
      }
    }
  }

  // ---- phase F: +conv_b, addLN over d (cross-wave via LDS), store ---------
#pragma unroll
  for (int i = 0; i < 4; i++) {
    float cb = conv_b[4 * wbase + i];
    cacc[i][0] += cb; cacc[i][1] += cb;
  }
#pragma unroll
  for (int jj = 0; jj < 2; jj++) {
    float s  = cacc[0][jj] + cacc[1][jj] + cacc[2][jj] + cacc[3][jj];
    float s2 = cacc[0][jj] * cacc[0][jj] + cacc[1][jj] * cacc[1][jj]
             + cacc[2][jj] * cacc[2][jj] + cacc[3][jj] * cacc[3][jj];
#pragma unroll
    for (int m = 8; m >= 1; m >>= 1) {   // reduce over lq (16-lane groups)
      s  += __shfl_xor(s, m);
      s2 += __shfl_xor(s2, m);
    }
    if (lq == 0) {
      s_ps[0][2 * ph + jj][wave] = s;
      s_ps[1][2 * ph + jj][wave] = s2;
    }
  }
  __syncthreads();
  if (t < CELLS) {
    float s  = s_ps[0][t][0] + s_ps[0][t][1] + s_ps[0][t][2] + s_ps[0][t][3];
    float s2 = s_ps[1][t][0] + s_ps[1][t][1] + s_ps[1][t][2] + s_ps[1][t][3];
    float mean = s * (1.f / 256.f);
    float var = s2 * (1.f / 256.f) - mean * mean;
    s_mv[t][0] = mean;
    s_mv[t][1] = rsqrtf(var + 1e-5f);
  }
  __syncthreads();
  {
    const int cell0  = 2 * ph;
    const int cglob0 = c0 + cell0;
    const float m0 = s_mv[cell0][0],     i0 = s_mv[cell0][1];
    const float m1 = s_mv[cell0 + 1][0], i1 = s_mv[cell0 + 1][1];
    const bool pair   = (cglob0 + 1) < C;
    const bool single = cglob0 < C;
#pragma unroll
    for (int i = 0; i < 4; i++) {
      int d = 4 * wbase + i;
      float lw = addln_w[d], lb = addln_b[d];
      float o0 = fmaf((cacc[i][0] - m0) * i0, lw, lb);
      float o1 = fmaf((cacc[i][1] - m1) * i1, lw, lb);
      size_t off = ((size_t)(b * DDIM + d) * MAXR + r) * MAXC + cglob0;
      if (pair) {
        float2 v; v.x = o0; v.y = o1;
        *reinterpret_cast<float2*>(&out[off]) = v;
      } else if (single) {
        out[off] = o0;
      }
    }
  }
}

// ---------------- safe fallback (no workspace): audited fp32 kernel --------
__global__ __launch_bounds__(256)
void k_main_safe(const float* __restrict__ feat,
                 const float* __restrict__ boxes,
                 const float* __restrict__ proj_w, const float* __restrict__ proj_b,
                 const float* __restrict__ bbox_w, const float* __restrict__ bbox_b,
                 const float* __restrict__ bboxln_w, const float* __restrict__ bboxln_b,
                 const float* __restrict__ conv_w, const float* __restrict__ conv_b,
                 const float* __restrict__ addln_w, const float* __restrict__ addln_b,
                 const int* __restrict__ nr, const int* __restrict__ nc,
                 float* __restrict__ out) {
  const int b  = blockIdx.z;
  const int r  = blockIdx.y;
  const int c0 = blockIdx.x * CELLS;
  const int R = load_count(nr, b);
  const int C = load_count(nc, b);
  if (r >= R || c0 >= C) return;

  const int t    = threadIdx.x;
  const int lane = t & 63;
  const int wave = t >> 6;
  const int dg = lane;
  const int cg = wave;

  __shared__ float s_buf[PTS * CIN_];
  __shared__ float s_w00[PTS], s_w01[PTS], s_w10[PTS], s_w11[PTS];
  __shared__ int   s_o00[PTS], s_o01[PTS], s_o10[PTS], s_o11[PTS];
  __shared__ float s_gx[PTS], s_gy[PTS], s_pm[PTS], s_pi[PTS];
  __shared__ float s_red[4][9];
  __shared__ float s_stat[9];

  {
    int d = t;
    float w0 = bbox_w[2 * d], w1 = bbox_w[2 * d + 1], bv = bbox_b[d];
    float v[9] = {w0, w1, bv, w0 * w0, w1 * w1, bv * bv, w0 * w1, w0 * bv, w1 * bv};
#pragma unroll
    for (int m = 32; m >= 1; m >>= 1) {
#pragma unroll
      for (int q = 0; q < 9; q++) v[q] += __shfl_xor(v[q], m);
    }
    if (lane == 0) {
#pragma unroll
      for (int q = 0; q < 9; q++) s_red[wave][q] = v[q];
    }
  }
  __syncthreads();
  if (t < 9) s_stat[t] = s_red[0][t] + s_red[1][t] + s_red[2][t] + s_red[3][t];
  __syncthreads();

  if (t < PTS) {
    int p = t;
    int cl = p >> 2, k = p & 3;
    int c = c0 + cl;
    const float* bp = boxes + ((((size_t)b * MAXR + r) * MAXC + c) * 4 + k) * 2;
    float bx = bp[0], by = bp[1];
    float px = bx * 0.25f - 0.5f;
    float py = by * 0.25f - 0.5f;
    float x0f = floorf(px), y0f = floorf(py);
    float wx1 = px - x0f, wx0 = 1.f - wx1;
    float wy1 = py - y0f, wy0 = 1.f - wy1;
    int x0 = (int)x0f, y0 = (int)y0f;
    int x1 = x0 + 1, y1 = y0 + 1;
    bool vx0 = (x0 >= 0) & (x0 < WW), vx1 = (x1 >= 0) & (x1 < WW);
    bool vy0 = (y0 >= 0) & (y0 < HH), vy1 = (y1 >= 0) & (y1 < HH);
    int x0c = min(max(x0, 0), WW - 1), x1c = min(max(x1, 0), WW - 1);
    int y0c = min(max(y0, 0), HH - 1), y1c = min(max(y1, 0), HH - 1);
    s_w00[p] = wx0 * wy0 * ((vx0 && vy0) ? 1.f : 0.f);
    s_w01[p] = wx1 * wy0 * ((vx1 && vy0) ? 1.f : 0.f);
    s_w10[p] = wx0 * wy1 * ((vx0 && vy1) ? 1.f : 0.f);
    s_w11[p] = wx1 * wy1 * ((vx1 && vy1) ? 1.f : 0.f);
    int base = b * CIN_ * HW;
    s_o00[p] = base + y0c * WW + x0c;
    s_o01[p] = base + y0c * WW + x1c;
    s_o10[p] = base + y1c * WW + x0c;
    s_o11[p] = base + y1c * WW + x1c;
    float gx = bx * (1.f / 256.f) - 1.f;
    float gy = by * (1.f / 256.f) - 1.f;
    s_gx[p] = gx; s_gy[p] = gy;
    const float inv256 = 1.f / 256.f;
    float mean = (s_stat[0] * gx + s_stat[1] * gy + s_stat[2]) * inv256;
    float e2 = (s_stat[3] * gx * gx + s_stat[4] * gy * gy + s_stat[5]
                + 2.f * (s_stat[6] * gx * gy + s_stat[7] * gx + s_stat[8] * gy)) * inv256;
    float var = e2 - mean * mean;
    s_pm[p] = mean;
    s_pi[p] = rsqrtf(var + 1e-5f);
  }
  __syncthreads();

#pragma unroll
  for (int j = 0; j < 8; j++) {
    int p = wave * 8 + j;
    float w00 = s_w00[p], w01 = s_w01[p], w10 = s_w10[p], w11 = s_w11[p];
    int o00 = s_o00[p], o01 = s_o01[p], o10 = s_o10[p], o11 = s_o11[p];
#pragma unroll
    for (int q = 0; q < 4; q++) {
      int ch = lane + 64 * q;
      int cho = ch * HW;
      float v = w00 * feat[o00 + cho] + w01 * feat[o01 + cho]
              + w10 * feat[o10 + cho] + w11 * feat[o11 + cho];
      s_buf[p * CIN_ + ch] = v;
    }
  }
  __syncthreads();

  float acc[4][8];
#pragma unroll
  for (int i = 0; i < 4; i++)
#pragma unroll
    for (int pp = 0; pp < 8; pp++) acc[i][pp] = 0.f;

  const float4* pw4 = (const float4*)proj_w;
  const float4* cf4 = (const float4*)s_buf;
#pragma unroll 2
  for (int k4 = 0; k4 < 64; k4++) {
    float4 wv[4];
#pragma unroll
    for (int i = 0; i < 4; i++) wv[i] = pw4[(4 * dg + i) * 64 + k4];
#pragma unroll
    for (int pp = 0; pp < 8; pp++) {
      float4 cv = cf4[(8 * cg + pp) * 64 + k4];
#pragma unroll
      for (int i = 0; i < 4; i++) {
        acc[i][pp] = fmaf(wv[i].x, cv.x, acc[i][pp]);
        acc[i][pp] = fmaf(wv[i].y, cv.y, acc[i][pp]);
        acc[i][pp] = fmaf(wv[i].z, cv.z, acc[i][pp]);
        acc[i][pp] = fmaf(wv[i].w, cv.w, acc[i][pp]);
      }
    }
  }
  __syncthreads();

  {
    float bw0[4], bw1[4], bbv[4], lnw[4], lnb[4], pbv[4];
#pragma unroll
    for (int i = 0; i < 4; i++) {
      int d = 4 * dg + i;
      bw0[i] = bbox_w[2 * d]; bw1[i] = bbox_w[2 * d + 1]; bbv[i] = bbox_b[d];
      lnw[i] = bboxln_w[d];   lnb[i] = bboxln_b[d];       pbv[i] = proj_b[d];
    }
#pragma unroll
    for (int i = 0; i < 4; i++) {
      int e = 4 * dg + i;
      int sw = dg & 7;
#pragma unroll
      for (int jj = 0; jj < 2; jj++) {
        int slot = (2 * cg + jj) ^ sw;
        float vv[4];
#pragma unroll
        for (int w = 0; w < 4; w++) {
          int pp = 4 * jj + w;
          int p = 8 * cg + pp;
          float tpos = bw0[i] * s_gx[p] + bw1[i] * s_gy[p] + bbv[i];
          float pos = (tpos - s_pm[p]) * s_pi[p] * lnw[i] + lnb[i];
          vv[w] = acc[i][pp] + pbv[i] + pos;
        }
        float4 v; v.x = vv[0]; v.y = vv[1]; v.z = vv[2]; v.w = vv[3];
        ((float4*)s_buf)[e * 8 + slot] = v;
      }
    }
  }
  __syncthreads();

  float cacc[4][2];
#pragma unroll
  for (int i = 0; i < 4; i++) { cacc[i][0] = 0.f; cacc[i][1] = 0.f; }

  const float4* cw4 = (const float4*)conv_w;
  const float4* fp4 = (const float4*)s_buf;
#pragma unroll 4
  for (int e = 0; e < 256; e++) {
    int sw = (e >> 2) & 7;
    float4 fv[2];
#pragma unroll
    for (int jj = 0; jj < 2; jj++) fv[jj] = fp4[e * 8 + ((2 * cg + jj) ^ sw)];
#pragma unroll
    for (int i = 0; i < 4; i++) {
      float4 wv = cw4[(4 * dg + i) * 256 + e];
#pragma unroll
      for (int jj = 0; jj < 2; jj++) {
        cacc[i][jj] = fmaf(wv.x, fv[jj].x, cacc[i][jj]);
        cacc[i][jj] = fmaf(wv.y, fv[jj].y, cacc[i][jj]);
        cacc[i][jj] = fmaf(wv.z, fv[jj].z, cacc[i][jj]);
        cacc[i][jj] = fmaf(wv.w, fv[jj].w, cacc[i][jj]);
      }
    }
  }

#pragma unroll
  for (int i = 0; i < 4; i++) {
    float cb = conv_b[4 * dg + i];
    cacc[i][0] += cb; cacc[i][1] += cb;
  }
#pragma unroll
  for (int jj = 0; jj < 2; jj++) {
    float s  = cacc[0][jj] + cacc[1][jj] + cacc[2][jj] + cacc[3][jj];
    float s2 = cacc[0][jj] * cacc[0][jj] + cacc[1][jj] * cacc[1][jj]
             + cacc[2][jj] * cacc[2][jj] + cacc[3][jj] * cacc[3][jj];
#pragma unroll
    for (int m = 32; m >= 1; m >>= 1) {
      s  += __shfl_xor(s, m);
      s2 += __shfl_xor(s2, m);
    }
    float mean = s * (1.f / 256.f);
    float var = s2 * (1.f / 256.f) - mean * mean;
    float inv = rsqrtf(var + 1e-5f);
    int cglob = c0 + 2 * cg + jj;
    if (cglob < C) {
#pragma unroll
      for (int i = 0; i < 4; i++) {
        int d = 4 * dg + i;
        float o = (cacc[i][jj] - mean) * inv * addln_w[d] + addln_b[d];
        out[((size_t)(b * DDIM + d) * MAXR + r) * MAXC + cglob] = o;
      }
    }
  }
}

// ---------------------------------------------------------------------------
extern "C" void kernel_launch(void* const* d_in, const int* in_sizes, int n_in,
                              void* d_out, int out_size, void* d_ws, size_t ws_size,
                              hipStream_t stream) {
  const int*   nr       = (const int*)d_in[0];
  const int*   nc       = (const int*)d_in[1];
  const float* feat     = (const float*)d_in[2];
  const float* boxes    = (const float*)d_in[3];
  const float* proj_w   = (const float*)d_in[4];
  const float* proj_b   = (const float*)d_in[5];
  const float* bbox_w   = (const float*)d_in[6];
  const float* bbox_b   = (const float*)d_in[7];
  const float* bboxln_w = (const float*)d_in[8];
  const float* bboxln_b = (const float*)d_in[9];
  const float* conv_w   = (const float*)d_in[10];
  const float* conv_b   = (const float*)d_in[11];
  const float* addln_w  = (const float*)d_in[12];
  const float* addln_b  = (const float*)d_in[13];
  float* out = (float*)d_out;

  {
    size_t total = (size_t)BB * DDIM * MAXR * MAXC / 4 + (size_t)BB * MAXR * MAXC;
    int blocks = (int)((total + 255) / 256);
    k_init<<<dim3(blocks), dim3(256), 0, stream>>>(out, nr, nc);
  }

  const size_t wbytes = WS_WBYTES;                                  // 1.25 MB
  const size_t tbytes = TF_FLOATS * sizeof(float);                  // 134 MB
  const dim3 grid(MAXC / CELLS, MAXR, BB);

  if (ws_size >= wbytes) {
    unsigned short* pwA_hi = (unsigned short*)d_ws;
    unsigned short* pwA_lo = pwA_hi + PWA_USHORTS;
    float* cwT = (float*)(pwA_lo + PWA_USHORTS);
    {
      int blocks = (PWA_USHORTS + CWT_FLOATS + 255) / 256;          // 1280
      k_wtrans<<<dim3(blocks), dim3(256), 0, stream>>>(proj_w, conv_w, pwA_hi, pwA_lo, cwT);
    }
    if (ws_size >= wbytes + tbytes) {
      float* tfeat = cwT + CWT_FLOATS;
      k_transpose<<<dim3(HW / 32, CIN_ / 32, BB), dim3(256), 0, stream>>>(feat, tfeat);
      k_main_fast<true><<<grid, dim3(256), 0, stream>>>(
          tfeat, boxes, pwA_hi, pwA_lo, proj_b, bbox_w, bbox_b, bboxln_w, bboxln_b,
          cwT, conv_b, addln_w, addln_b, nr, nc, out);
    } else {
      k_main_fast<false><<<grid, dim3(256), 0, stream>>>(
          feat, boxes, pwA_hi, pwA_lo, proj_b, bbox_w, bbox_b, bboxln_w, bboxln_b,
          cwT, conv_b, addln_w, addln_b, nr, nc, out);
    }
  } else {
    k_main_safe<<<grid, dim3(256), 0, stream>>>(
        feat, boxes, proj_w, proj_b, bbox_w, bbox_b, bboxln_w, bboxln_b,
        conv_w, conv_b, addln_w, addln_b, nr, nc, out);
  }
}

// Round 7
// 540.970 us; speedup vs baseline: 1.4028x; 1.4028x over previous
//
#include <hip/hip_runtime.h>
#include <cstddef>
#include <cstdint>

// ---------------------------------------------------------------------------
// CornerPosFeatExtractor fused kernel, round 7.
// r6 post-mortem: latency-bound (558us, VALU 24%, MFMA 2%, HBM 4%) — phase E
// fp32 conv issued 1024 quarter-replicated VMEM/wave ~serialized at L2 latency.
// NEW: conv on MFMA (split-bf16, 4-pass) with pre-packed per-lane A-fragments
// (coalesced 1KB loads, 4x fewer VMEM); fp staged as bf16 hi/lo fpT[cell][ek]
// in LDS; per-d params staged in s_prm (kills broadcast gathers); k_init
// folded into k_main (zero-fill in-kernel).
//
// MFMA mapping (16x16x32 bf16, HW-validated in r6 via proj):
//   A row = l&15, k = (l>>4)*8+j (pre-packed);  B col = l&15, same k;
//   D row = (l>>4)*4+reg, col = l&15.
// Conv GEMM: out[d][cell] = sum_ek cwflat[d][ek] * fp[ek][cell], ek = e*4+corner.
// ---------------------------------------------------------------------------

#define BB    8
#define CIN_  256
#define DDIM  256
#define HH    128
#define WW    128
#define HW    (HH*WW)
#define MAXR  64
#define MAXC  64
#define CELLS 8
#define PTS   32   // 4*CELLS

#define PWA_USHORTS 65536            // 256x256 per plane
#define CWA_USHORTS 262144           // 256x1024 per plane
#define WS_WBYTES   ((size_t)(PWA_USHORTS + CWA_USHORTS) * 2 * sizeof(unsigned short))
#define TF_FLOATS   ((size_t)BB*CIN_*HW)

#define FPT_STRIDE  1032             // ushorts per cell row (1024 + 8 pad, 16B-mult)
#define FPT_PLANE   8256             // 8 cells * 1032 (ushorts)
#define SBUF_FLOATS 8256             // 33024 B: max(cf 32768 B, fpT 33024 B)

typedef __attribute__((ext_vector_type(8))) short bf16x8;
typedef __attribute__((ext_vector_type(4))) float f32x4;

__device__ __forceinline__ unsigned short f2bf(float x) {
  unsigned u = __float_as_uint(x);
  return (unsigned short)((u + 0x7FFFu + ((u >> 16) & 1u)) >> 16);  // RNE
}
__device__ __forceinline__ float bf2f(unsigned short b) {
  return __uint_as_float(((unsigned)b) << 16);
}

// num_rows/num_cols: np.int64 in reference; detect int32 vs int64 at runtime
// (counts are all >=24, so word[1]==0 iff int64 little-endian).
__device__ __forceinline__ int load_count(const int* __restrict__ p, int idx) {
  return (p[1] == 0) ? p[2 * idx] : p[idx];
}

// ---------------- init (safe tier only): zero output + mask ----------------
__global__ void k_init(float* __restrict__ out,
                       const int* __restrict__ nr, const int* __restrict__ nc) {
  const size_t NAL4 = (size_t)BB * DDIM * MAXR * MAXC / 4;
  size_t i = (size_t)blockIdx.x * blockDim.x + threadIdx.x;
  if (i < NAL4) {
    ((float4*)out)[i] = make_float4(0.f, 0.f, 0.f, 0.f);
  } else {
    size_t mi = i - NAL4;
    const size_t NM = (size_t)BB * MAXR * MAXC;
    if (mi < NM) {
      int b = (int)(mi / (MAXR * MAXC));
      int rc = (int)(mi % (MAXR * MAXC));
      int r = rc / MAXC, c = rc % MAXC;
      int R = load_count(nr, b), C = load_count(nc, b);
      out[(size_t)BB * DDIM * MAXR * MAXC + mi] = (r < R && c < C) ? 1.f : 0.f;
    }
  }
}

// ---------------- weight prep: MFMA A-fragments (split bf16) ---------------
// pwA_{hi,lo}[((dt*8 + kc)*64 + l)*8 + j] = split(proj_w[dt*16+(l&15)][kc*32+(l>>4)*8+j])
// cwA_{hi,lo}[((dt*32 + kc)*64 + l)*8 + j] = split(conv_w[(dt*16+(l&15))*1024 + kc*32+(l>>4)*8+j])
__global__ void k_wtrans(const float* __restrict__ pw, const float* __restrict__ cw,
                         unsigned short* __restrict__ pwA_hi,
                         unsigned short* __restrict__ pwA_lo,
                         unsigned short* __restrict__ cwA_hi,
                         unsigned short* __restrict__ cwA_lo) {
  int i = blockIdx.x * 256 + threadIdx.x;
  if (i < PWA_USHORTS) {
    int dt = i >> 12, kc = (i >> 9) & 7, ln = (i >> 3) & 63, j = i & 7;
    int d = dt * 16 + (ln & 15);
    int k = kc * 32 + ((ln >> 4) << 3) + j;
    float v = pw[d * 256 + k];
    unsigned short h = f2bf(v);
    pwA_hi[i] = h;
    pwA_lo[i] = f2bf(v - bf2f(h));
  } else {
    int j = i - PWA_USHORTS;
    if (j < CWA_USHORTS) {
      int jj = j & 7, l = (j >> 3) & 63, kc = (j >> 9) & 31, dt = j >> 14;
      int d = dt * 16 + (l & 15);
      int ek = kc * 32 + ((l >> 4) << 3) + jj;
      float v = cw[d * 1024 + ek];
      unsigned short h = f2bf(v);
      cwA_hi[j] = h;
      cwA_lo[j] = f2bf(v - bf2f(h));
    }
  }
}

// ---------------- transpose feat NCHW -> NHWC (float4 both sides) ----------
__global__ __launch_bounds__(256)
void k_transpose(const float* __restrict__ feat, float* __restrict__ tfeat) {
  __shared__ float tile[32][33];
  const int pix0 = blockIdx.x * 32;
  const int ch0  = blockIdx.y * 32;
  const int b    = blockIdx.z;
  const int t  = threadIdx.x;
  const int tx = t & 7;
  const int ty = t >> 3;
  const float4* fb4 = (const float4*)(feat + (size_t)b * CIN_ * HW);
  float4*       tb4 = (float4*)(tfeat + (size_t)b * CIN_ * HW);

  float4 v = fb4[((size_t)(ch0 + ty) * HW + pix0) / 4 + tx];
  tile[ty][4 * tx + 0] = v.x;
  tile[ty][4 * tx + 1] = v.y;
  tile[ty][4 * tx + 2] = v.z;
  tile[ty][4 * tx + 3] = v.w;
  __syncthreads();

  float4 o;
  o.x = tile[4 * tx + 0][ty];
  o.y = tile[4 * tx + 1][ty];
  o.z = tile[4 * tx + 2][ty];
  o.w = tile[4 * tx + 3][ty];
  tb4[((size_t)(pix0 + ty) * CIN_ + ch0) / 4 + tx] = o;
}

// ---------------- fused main kernel (MFMA proj + MFMA conv) ----------------
template<bool NHWC>
__global__ __launch_bounds__(256)
void k_main_fast(const float* __restrict__ feat,   // NHWC ? tfeat : original
                 const float* __restrict__ boxes,
                 const unsigned short* __restrict__ pwA_hi,
                 const unsigned short* __restrict__ pwA_lo,
                 const unsigned short* __restrict__ cwA_hi,
                 const unsigned short* __restrict__ cwA_lo,
                 const float* __restrict__ proj_b,
                 const float* __restrict__ bbox_w, const float* __restrict__ bbox_b,
                 const float* __restrict__ bboxln_w, const float* __restrict__ bboxln_b,
                 const float* __restrict__ conv_b,
                 const float* __restrict__ addln_w, const float* __restrict__ addln_b,
                 const int* __restrict__ nr, const int* __restrict__ nc,
                 float* __restrict__ out) {
  const int b  = blockIdx.z;
  const int r  = blockIdx.y;
  const int c0 = blockIdx.x * CELLS;
  const int R = load_count(nr, b);
  const int C = load_count(nc, b);
  const int t = threadIdx.x;

  const size_t MASK_OFF = (size_t)BB * DDIM * MAXR * MAXC;

  // -------- invalid block: zero-fill our output slice + mask, exit ---------
  if (r >= R || c0 >= C) {
    float4 z = make_float4(0.f, 0.f, 0.f, 0.f);
    size_t off = ((size_t)(b * DDIM + t) * MAXR + r) * MAXC + c0;
    *reinterpret_cast<float4*>(&out[off])     = z;   // c0 % 8 == 0: aligned
    *reinterpret_cast<float4*>(&out[off + 4]) = z;
    if (t < CELLS) out[MASK_OFF + ((size_t)b * MAXR + r) * MAXC + c0 + t] = 0.f;
    return;
  }

  const int lane = t & 63;
  const int wave = t >> 6;

  __shared__ __align__(16) float s_buf[SBUF_FLOATS];  // cf bf16 | fpT bf16
  __shared__ float s_w00[PTS], s_w01[PTS], s_w10[PTS], s_w11[PTS];
  __shared__ int   s_o00[PTS], s_o01[PTS], s_o10[PTS], s_o11[PTS];
  __shared__ float s_gx[PTS], s_gy[PTS], s_pm[PTS], s_pi[PTS];
  __shared__ float s_red[4][9];
  __shared__ float s_stat[9];
  __shared__ float s_prm[DDIM][10];      // pc0,pc1,pc2,lnw,lnb,pjb,cb,alw,alb
  __shared__ float s_ps[2][CELLS][4];
  __shared__ float s_mv[CELLS][2];

  // ---- phase 0: bbox moments (for analytic pos-LN) + per-d param staging --
  {
    int d = t;
    float w0 = bbox_w[2 * d], w1 = bbox_w[2 * d + 1], bv = bbox_b[d];
    float lnw = bboxln_w[d], lnb = bboxln_b[d];
    s_prm[d][0] = w0 * lnw;
    s_prm[d][1] = w1 * lnw;
    s_prm[d][2] = bv * lnw;
    s_prm[d][3] = lnw;
    s_prm[d][4] = lnb;
    s_prm[d][5] = proj_b[d];
    s_prm[d][6] = conv_b[d];
    s_prm[d][7] = addln_w[d];
    s_prm[d][8] = addln_b[d];
    float v[9] = {w0, w1, bv, w0 * w0, w1 * w1, bv * bv, w0 * w1, w0 * bv, w1 * bv};
#pragma unroll
    for (int m = 32; m >= 1; m >>= 1) {
#pragma unroll
      for (int q = 0; q < 9; q++) v[q] += __shfl_xor(v[q], m);
    }
    if (lane == 0) {
#pragma unroll
      for (int q = 0; q < 9; q++) s_red[wave][q] = v[q];
    }
  }
  __syncthreads();
  if (t < 9) s_stat[t] = s_red[0][t] + s_red[1][t] + s_red[2][t] + s_red[3][t];
  __syncthreads();

  // ---- phase A: per-point sampling params + pos-LN mean/inv ----
  if (t < PTS) {
    int p = t;
    int cl = p >> 2, k = p & 3;
    int c = c0 + cl;
    const float* bp = boxes + ((((size_t)b * MAXR + r) * MAXC + c) * 4 + k) * 2;
    float bx = bp[0], by = bp[1];
    float px = bx * 0.25f - 0.5f;           // g=boxes*0.25; px=(gx+1)W/2-0.5
    float py = by * 0.25f - 0.5f;
    float x0f = floorf(px), y0f = floorf(py);
    float wx1 = px - x0f, wx0 = 1.f - wx1;
    float wy1 = py - y0f, wy0 = 1.f - wy1;
    int x0 = (int)x0f, y0 = (int)y0f;
    int x1 = x0 + 1, y1 = y0 + 1;
    bool vx0 = (x0 >= 0) & (x0 < WW), vx1 = (x1 >= 0) & (x1 < WW);
    bool vy0 = (y0 >= 0) & (y0 < HH), vy1 = (y1 >= 0) & (y1 < HH);
    int x0c = min(max(x0, 0), WW - 1), x1c = min(max(x1, 0), WW - 1);
    int y0c = min(max(y0, 0), HH - 1), y1c = min(max(y1, 0), HH - 1);
    s_w00[p] = wx0 * wy0 * ((vx0 && vy0) ? 1.f : 0.f);
    s_w01[p] = wx1 * wy0 * ((vx1 && vy0) ? 1.f : 0.f);
    s_w10[p] = wx0 * wy1 * ((vx0 && vy1) ? 1.f : 0.f);
    s_w11[p] = wx1 * wy1 * ((vx1 && vy1) ? 1.f : 0.f);
    if (NHWC) {
      int base = b * HW;
      s_o00[p] = (base + y0c * WW + x0c) << 8;
      s_o01[p] = (base + y0c * WW + x1c) << 8;
      s_o10[p] = (base + y1c * WW + x0c) << 8;
      s_o11[p] = (base + y1c * WW + x1c) << 8;
    } else {
      int base = b * CIN_ * HW;
      s_o00[p] = base + y0c * WW + x0c;
      s_o01[p] = base + y0c * WW + x1c;
      s_o10[p] = base + y1c * WW + x0c;
      s_o11[p] = base + y1c * WW + x1c;
    }
    float gx = bx * (1.f / 256.f) - 1.f;
    float gy = by * (1.f / 256.f) - 1.f;
    s_gx[p] = gx; s_gy[p] = gy;
    const float inv256 = 1.f / 256.f;
    float mean = (s_stat[0] * gx + s_stat[1] * gy + s_stat[2]) * inv256;
    float e2 = (s_stat[3] * gx * gx + s_stat[4] * gy * gy + s_stat[5]
                + 2.f * (s_stat[6] * gx * gy + s_stat[7] * gx + s_stat[8] * gy)) * inv256;
    float var = e2 - mean * mean;
    s_pm[p] = mean;
    s_pi[p] = rsqrtf(var + 1e-5f);
  }
  __syncthreads();

  // ---- phase B: bilinear-sample -> cf bf16 hi/lo planes -------------------
  // cf_{hi,lo}[p][256 ch], physical chunk(8ch) = logical chunk ^ (p&7).
  {
    unsigned short* cfh = (unsigned short*)s_buf;
    unsigned short* cfl = cfh + PTS * CIN_;
    if (NHWC) {
      const float4* f4 = (const float4*)feat;
#pragma unroll
      for (int j = 0; j < 8; j++) {
        int p = wave * 8 + j;
        float w00 = s_w00[p], w01 = s_w01[p], w10 = s_w10[p], w11 = s_w11[p];
        float4 v00 = f4[(s_o00[p] >> 2) + lane];
        float4 v01 = f4[(s_o01[p] >> 2) + lane];
        float4 v10 = f4[(s_o10[p] >> 2) + lane];
        float4 v11 = f4[(s_o11[p] >> 2) + lane];
        float4 a;
        a.x = w00 * v00.x + w01 * v01.x + w10 * v10.x + w11 * v11.x;
        a.y = w00 * v00.y + w01 * v01.y + w10 * v10.y + w11 * v11.y;
        a.z = w00 * v00.z + w01 * v01.z + w10 * v10.z + w11 * v11.z;
        a.w = w00 * v00.w + w01 * v01.w + w10 * v10.w + w11 * v11.w;
        unsigned short h0 = f2bf(a.x), h1 = f2bf(a.y), h2 = f2bf(a.z), h3 = f2bf(a.w);
        unsigned long long hp = (unsigned long long)h0 | ((unsigned long long)h1 << 16)
                              | ((unsigned long long)h2 << 32) | ((unsigned long long)h3 << 48);
        unsigned short l0 = f2bf(a.x - bf2f(h0)), l1 = f2bf(a.y - bf2f(h1));
        unsigned short l2 = f2bf(a.z - bf2f(h2)), l3 = f2bf(a.w - bf2f(h3));
        unsigned long long lp = (unsigned long long)l0 | ((unsigned long long)l1 << 16)
                              | ((unsigned long long)l2 << 32) | ((unsigned long long)l3 << 48);
        int base = p * 256 + ((((lane >> 1) ^ (p & 7)) << 3) + ((lane & 1) << 2));
        *(unsigned long long*)(cfh + base) = hp;
        *(unsigned long long*)(cfl + base) = lp;
      }
    } else {
#pragma unroll
      for (int j = 0; j < 8; j++) {
        int p = wave * 8 + j;
        float w00 = s_w00[p], w01 = s_w01[p], w10 = s_w10[p], w11 = s_w11[p];
        int o00 = s_o00[p], o01 = s_o01[p], o10 = s_o10[p], o11 = s_o11[p];
#pragma unroll
        for (int q = 0; q < 4; q++) {
          int ch = lane + 64 * q;
          int cho = ch * HW;
          float v = w00 * feat[o00 + cho] + w01 * feat[o01 + cho]
                  + w10 * feat[o10 + cho] + w11 * feat[o11 + cho];
          unsigned short h = f2bf(v);
          int bidx = p * 256 + ((((ch >> 3) ^ (p & 7)) << 3) + (ch & 7));
          cfh[bidx] = h;
          cfl[bidx] = f2bf(v - bf2f(h));
        }
      }
    }
  }
  __syncthreads();

  // ---- phase C: proj via MFMA (split hi/lo, 3 passes) — r6-validated ------
  f32x4 pacc[4][2];
#pragma unroll
  for (int dt = 0; dt < 4; dt++)
#pragma unroll
    for (int pt = 0; pt < 2; pt++)
      pacc[dt][pt] = (f32x4){0.f, 0.f, 0.f, 0.f};

  {
    const bf16x8* gAh = (const bf16x8*)pwA_hi;
    const bf16x8* gAl = (const bf16x8*)pwA_lo;
    const unsigned short* cfh = (const unsigned short*)s_buf;
    const unsigned short* cfl = cfh + PTS * CIN_;
#pragma unroll 2
    for (int kc = 0; kc < 8; kc++) {
      bf16x8 ah[4], al[4];
#pragma unroll
      for (int dt = 0; dt < 4; dt++) {
        int gt = wave * 4 + dt;
        ah[dt] = gAh[(gt * 8 + kc) * 64 + lane];
        al[dt] = gAl[(gt * 8 + kc) * 64 + lane];
      }
#pragma unroll
      for (int pt = 0; pt < 2; pt++) {
        int p = pt * 16 + (lane & 15);
        int ch = (kc * 4 + (lane >> 4)) ^ (p & 7);
        bf16x8 bh = *(const bf16x8*)(cfh + p * 256 + ch * 8);
        bf16x8 bl = *(const bf16x8*)(cfl + p * 256 + ch * 8);
#pragma unroll
        for (int dt = 0; dt < 4; dt++) {
          pacc[dt][pt] = __builtin_amdgcn_mfma_f32_16x16x32_bf16(ah[dt], bh, pacc[dt][pt], 0, 0, 0);
          pacc[dt][pt] = __builtin_amdgcn_mfma_f32_16x16x32_bf16(ah[dt], bl, pacc[dt][pt], 0, 0, 0);
          pacc[dt][pt] = __builtin_amdgcn_mfma_f32_16x16x32_bf16(al[dt], bh, pacc[dt][pt], 0, 0, 0);
        }
      }
    }
  }
  __syncthreads();   // cf dead; s_buf becomes fpT bf16 planes

  // ---- phase D: fp = proj + proj_b + posLN -> fpT bf16 hi/lo --------------
  // Writer: e = wave*64+dt*16+q*4+reg (D-frag row), p = pt*16+col. ek = e*4+corner.
  {
    const int q   = lane >> 4;
    const int col = lane & 15;
    unsigned short* fph = (unsigned short*)s_buf;
    unsigned short* fpl = fph + FPT_PLANE;
#pragma unroll
    for (int dt = 0; dt < 4; dt++) {
#pragma unroll
      for (int reg = 0; reg < 4; reg++) {
        int e = wave * 64 + dt * 16 + q * 4 + reg;
        float pc0 = s_prm[e][0], pc1 = s_prm[e][1], pc2 = s_prm[e][2];
        float lnw = s_prm[e][3], lnb = s_prm[e][4], pjb = s_prm[e][5];
#pragma unroll
        for (int pt = 0; pt < 2; pt++) {
          int p = pt * 16 + col;
          float pip = s_pi[p];
          float pos = pip * (pc0 * s_gx[p] + pc1 * s_gy[p] + pc2)
                    - pip * s_pm[p] * lnw + lnb;
          float val = pacc[dt][pt][reg] + pjb + pos;
          unsigned short h = f2bf(val);
          unsigned short l = f2bf(val - bf2f(h));
          int idx = (p >> 2) * FPT_STRIDE + e * 4 + (p & 3);
          fph[idx] = h;
          fpl[idx] = l;
        }
      }
    }
  }
  __syncthreads();

  // ---- phase E: conv via MFMA (split hi/lo, 4 passes) ---------------------
  // B col = lane&15 -> cell (cols 8-15 read col-8: harmless duplicates).
  f32x4 cacc[4];
#pragma unroll
  for (int dt = 0; dt < 4; dt++) cacc[dt] = (f32x4){0.f, 0.f, 0.f, 0.f};

  {
    const bf16x8* gCh = (const bf16x8*)cwA_hi;
    const bf16x8* gCl = (const bf16x8*)cwA_lo;
    const unsigned short* fph = (const unsigned short*)s_buf;
    const unsigned short* fpl = fph + FPT_PLANE;
    const int colB = lane & 7;
    const int kq   = lane >> 4;
#pragma unroll 2
    for (int kc = 0; kc < 32; kc++) {
      bf16x8 bh = *(const bf16x8*)(fph + colB * FPT_STRIDE + kc * 32 + kq * 8);
      bf16x8 bl = *(const bf16x8*)(fpl + colB * FPT_STRIDE + kc * 32 + kq * 8);
#pragma unroll
      for (int dt = 0; dt < 4; dt++) {
        int gt = wave * 4 + dt;
        bf16x8 ahh = gCh[(gt * 32 + kc) * 64 + lane];
        bf16x8 alo = gCl[(gt * 32 + kc) * 64 + lane];
        cacc[dt] = __builtin_amdgcn_mfma_f32_16x16x32_bf16(ahh, bh, cacc[dt], 0, 0, 0);
        cacc[dt] = __builtin_amdgcn_mfma_f32_16x16x32_bf16(ahh, bl, cacc[dt], 0, 0, 0);
        cacc[dt] = __builtin_amdgcn_mfma_f32_16x16x32_bf16(alo, bh, cacc[dt], 0, 0, 0);
        cacc[dt] = __builtin_amdgcn_mfma_f32_16x16x32_bf16(alo, bl, cacc[dt], 0, 0, 0);
      }
    }
  }

  // ---- phase F: +conv_b, addLN over d, store ------------------------------
  // Lane holds conv[d = wave*64+dt*16+q*4+reg][cell = lane&15] (cols>=8 dup).
  {
    const int q   = lane >> 4;
    const int col = lane & 15;
    float s = 0.f, s2 = 0.f;
#pragma unroll
    for (int dt = 0; dt < 4; dt++) {
#pragma unroll
      for (int reg = 0; reg < 4; reg++) {
        int d = wave * 64 + dt * 16 + q * 4 + reg;
        float y = cacc[dt][reg] + s_prm[d][6];
        cacc[dt][reg] = y;
        s += y;
        s2 += y * y;
      }
    }
    s  += __shfl_xor(s, 16);  s  += __shfl_xor(s, 32);   // sum over q
    s2 += __shfl_xor(s2, 16); s2 += __shfl_xor(s2, 32);
    if (q == 0 && col < CELLS) {
      s_ps[0][col][wave] = s;
      s_ps[1][col][wave] = s2;
    }
  }
  __syncthreads();
  if (t < CELLS) {
    float s  = s_ps[0][t][0] + s_ps[0][t][1] + s_ps[0][t][2] + s_ps[0][t][3];
    float s2 = s_ps[1][t][0] + s_ps[1][t][1] + s_ps[1][t][2] + s_ps[1][t][3];
    float mean = s * (1.f / 256.f);
    float var = s2 * (1.f / 256.f) - mean * mean;
    s_mv[t][0] = mean;
    s_mv[t][1] = rsqrtf(var + 1e-5f);
    // mask for this block's 8 columns
    out[MASK_OFF + ((size_t)b * MAXR + r) * MAXC + c0 + t] = (c0 + (int)t < C) ? 1.f : 0.f;
  }
  __syncthreads();
  {
    const int q   = lane >> 4;
    const int col = lane & 15;
    if (col < CELLS) {
      int cglob = c0 + col;
      bool vc = cglob < C;
      float mean = s_mv[col][0], inv = s_mv[col][1];
#pragma unroll
      for (int dt = 0; dt < 4; dt++) {
#pragma unroll
        for (int reg = 0; reg < 4; reg++) {
          int d = wave * 64 + dt * 16 + q * 4 + reg;
          float o = fmaf((cacc[dt][reg] - mean) * inv, s_prm[d][7], s_prm[d][8]);
          out[((size_t)(b * DDIM + d) * MAXR + r) * MAXC + cglob] = vc ? o : 0.f;
        }
      }
    }
  }
}

// ---------------- safe fallback (no workspace): audited fp32 kernel --------
__global__ __launch_bounds__(256)
void k_main_safe(const float* __restrict__ feat,
                 const float* __restrict__ boxes,
                 const float* __restrict__ proj_w, const float* __restrict__ proj_b,
                 const float* __restrict__ bbox_w, const float* __restrict__ bbox_b,
                 const float* __restrict__ bboxln_w, const float* __restrict__ bboxln_b,
                 const float* __restrict__ conv_w, const float* __restrict__ conv_b,
                 const float* __restrict__ addln_w, const float* __restrict__ addln_b,
                 const int* __restrict__ nr, const int* __restrict__ nc,
                 float* __restrict__ out) {
  const int b  = blockIdx.z;
  const int r  = blockIdx.y;
  const int c0 = blockIdx.x * CELLS;
  const int R = load_count(nr, b);
  const int C = load_count(nc, b);
  if (r >= R || c0 >= C) return;

  const int t    = threadIdx.x;
  const int lane = t & 63;
  const int wave = t >> 6;
  const int dg = lane;
  const int cg = wave;

  __shared__ float s_buf[PTS * CIN_];
  __shared__ float s_w00[PTS], s_w01[PTS], s_w10[PTS], s_w11[PTS];
  __shared__ int   s_o00[PTS], s_o01[PTS], s_o10[PTS], s_o11[PTS];
  __shared__ float s_gx[PTS], s_gy[PTS], s_pm[PTS], s_pi[PTS];
  __shared__ float s_red[4][9];
  __shared__ float s_stat[9];

  {
    int d = t;
    float w0 = bbox_w[2 * d], w1 = bbox_w[2 * d + 1], bv = bbox_b[d];
    float v[9] = {w0, w1, bv, w0 * w0, w1 * w1, bv * bv, w0 * w1, w0 * bv, w1 * bv};
#pragma unroll
    for (int m = 32; m >= 1; m >>= 1) {
#pragma unroll
      for (int q = 0; q < 9; q++) v[q] += __shfl_xor(v[q], m);
    }
    if (lane == 0) {
#pragma unroll
      for (int q = 0; q < 9; q++) s_red[wave][q] = v[q];
    }
  }
  __syncthreads();
  if (t < 9) s_stat[t] = s_red[0][t] + s_red[1][t] + s_red[2][t] + s_red[3][t];
  __syncthreads();

  if (t < PTS) {
    int p = t;
    int cl = p >> 2, k = p & 3;
    int c = c0 + cl;
    const float* bp = boxes + ((((size_t)b * MAXR + r) * MAXC + c) * 4 + k) * 2;
    float bx = bp[0], by = bp[1];
    float px = bx * 0.25f - 0.5f;
    float py = by * 0.25f - 0.5f;
    float x0f = floorf(px), y0f = floorf(py);
    float wx1 = px - x0f, wx0 = 1.f - wx1;
    float wy1 = py - y0f, wy0 = 1.f - wy1;
    int x0 = (int)x0f, y0 = (int)y0f;
    int x1 = x0 + 1, y1 = y0 + 1;
    bool vx0 = (x0 >= 0) & (x0 < WW), vx1 = (x1 >= 0) & (x1 < WW);
    bool vy0 = (y0 >= 0) & (y0 < HH), vy1 = (y1 >= 0) & (y1 < HH);
    int x0c = min(max(x0, 0), WW - 1), x1c = min(max(x1, 0), WW - 1);
    int y0c = min(max(y0, 0), HH - 1), y1c = min(max(y1, 0), HH - 1);
    s_w00[p] = wx0 * wy0 * ((vx0 && vy0) ? 1.f : 0.f);
    s_w01[p] = wx1 * wy0 * ((vx1 && vy0) ? 1.f : 0.f);
    s_w10[p] = wx0 * wy1 * ((vx0 && vy1) ? 1.f : 0.f);
    s_w11[p] = wx1 * wy1 * ((vx1 && vy1) ? 1.f : 0.f);
    int base = b * CIN_ * HW;
    s_o00[p] = base + y0c * WW + x0c;
    s_o01[p] = base + y0c * WW + x1c;
    s_o10[p] = base + y1c * WW + x0c;
    s_o11[p] = base + y1c * WW + x1c;
    float gx = bx * (1.f / 256.f) - 1.f;
    float gy = by * (1.f / 256.f) - 1.f;
    s_gx[p] = gx; s_gy[p] = gy;
    const float inv256 = 1.f / 256.f;
    float mean = (s_stat[0] * gx + s_stat[1] * gy + s_stat[2]) * inv256;
    float e2 = (s_stat[3] * gx * gx + s_stat[4] * gy * gy + s_stat[5]
                + 2.f * (s_stat[6] * gx * gy + s_stat[7] * gx + s_stat[8] * gy)) * inv256;
    float var = e2 - mean * mean;
    s_pm[p] = mean;
    s_pi[p] = rsqrtf(var + 1e-5f);
  }
  __syncthreads();

#pragma unroll
  for (int j = 0; j < 8; j++) {
    int p = wave * 8 + j;
    float w00 = s_w00[p], w01 = s_w01[p], w10 = s_w10[p], w11 = s_w11[p];
    int o00 = s_o00[p], o01 = s_o01[p], o10 = s_o10[p], o11 = s_o11[p];
#pragma unroll
    for (int q = 0; q < 4; q++) {
      int ch = lane + 64 * q;
      int cho = ch * HW;
      float v = w00 * feat[o00 + cho] + w01 * feat[o01 + cho]
              + w10 * feat[o10 + cho] + w11 * feat[o11 + cho];
      s_buf[p * CIN_ + ch] = v;
    }
  }
  __syncthreads();

  float acc[4][8];
#pragma unroll
  for (int i = 0; i < 4; i++)
#pragma unroll
    for (int pp = 0; pp < 8; pp++) acc[i][pp] = 0.f;

  const float4* pw4 = (const float4*)proj_w;
  const float4* cf4 = (const float4*)s_buf;
#pragma unroll 2
  for (int k4 = 0; k4 < 64; k4++) {
    float4 wv[4];
#pragma unroll
    for (int i = 0; i < 4; i++) wv[i] = pw4[(4 * dg + i) * 64 + k4];
#pragma unroll
    for (int pp = 0; pp < 8; pp++) {
      float4 cv = cf4[(8 * cg + pp) * 64 + k4];
#pragma unroll
      for (int i = 0; i < 4; i++) {
        acc[i][pp] = fmaf(wv[i].x, cv.x, acc[i][pp]);
        acc[i][pp] = fmaf(wv[i].y, cv.y, acc[i][pp]);
        acc[i][pp] = fmaf(wv[i].z, cv.z, acc[i][pp]);
        acc[i][pp] = fmaf(wv[i].w, cv.w, acc[i][pp]);
      }
    }
  }
  __syncthreads();

  {
    float bw0[4], bw1[4], bbv[4], lnw[4], lnb[4], pbv[4];
#pragma unroll
    for (int i = 0; i < 4; i++) {
      int d = 4 * dg + i;
      bw0[i] = bbox_w[2 * d]; bw1[i] = bbox_w[2 * d + 1]; bbv[i] = bbox_b[d];
      lnw[i] = bboxln_w[d];   lnb[i] = bboxln_b[d];       pbv[i] = proj_b[d];
    }
#pragma unroll
    for (int i = 0; i < 4; i++) {
      int e = 4 * dg + i;
      int sw = dg & 7;
#pragma unroll
      for (int jj = 0; jj < 2; jj++) {
        int slot = (2 * cg + jj) ^ sw;
        float vv[4];
#pragma unroll
        for (int w = 0; w < 4; w++) {
          int pp = 4 * jj + w;
          int p = 8 * cg + pp;
          float tpos = bw0[i] * s_gx[p] + bw1[i] * s_gy[p] + bbv[i];
          float pos = (tpos - s_pm[p]) * s_pi[p] * lnw[i] + lnb[i];
          vv[w] = acc[i][pp] + pbv[i] + pos;
        }
        float4 v; v.x = vv[0]; v.y = vv[1]; v.z = vv[2]; v.w = vv[3];
        ((float4*)s_buf)[e * 8 + slot] = v;
      }
    }
  }
  __syncthreads();

  float cacc[4][2];
#pragma unroll
  for (int i = 0; i < 4; i++) { cacc[i][0] = 0.f; cacc[i][1] = 0.f; }

  const float4* cw4 = (const float4*)conv_w;
  const float4* fp4 = (const float4*)s_buf;
#pragma unroll 4
  for (int e = 0; e < 256; e++) {
    int sw = (e >> 2) & 7;
    float4 fv[2];
#pragma unroll
    for (int jj = 0; jj < 2; jj++) fv[jj] = fp4[e * 8 + ((2 * cg + jj) ^ sw)];
#pragma unroll
    for (int i = 0; i < 4; i++) {
      float4 wv = cw4[(4 * dg + i) * 256 + e];
#pragma unroll
      for (int jj = 0; jj < 2; jj++) {
        cacc[i][jj] = fmaf(wv.x, fv[jj].x, cacc[i][jj]);
        cacc[i][jj] = fmaf(wv.y, fv[jj].y, cacc[i][jj]);
        cacc[i][jj] = fmaf(wv.z, fv[jj].z, cacc[i][jj]);
        cacc[i][jj] = fmaf(wv.w, fv[jj].w, cacc[i][jj]);
      }
    }
  }

#pragma unroll
  for (int i = 0; i < 4; i++) {
    float cb = conv_b[4 * dg + i];
    cacc[i][0] += cb; cacc[i][1] += cb;
  }
#pragma unroll
  for (int jj = 0; jj < 2; jj++) {
    float s  = cacc[0][jj] + cacc[1][jj] + cacc[2][jj] + cacc[3][jj];
    float s2 = cacc[0][jj] * cacc[0][jj] + cacc[1][jj] * cacc[1][jj]
             + cacc[2][jj] * cacc[2][jj] + cacc[3][jj] * cacc[3][jj];
#pragma unroll
    for (int m = 32; m >= 1; m >>= 1) {
      s  += __shfl_xor(s, m);
      s2 += __shfl_xor(s2, m);
    }
    float mean = s * (1.f / 256.f);
    float var = s2 * (1.f / 256.f) - mean * mean;
    float inv = rsqrtf(var + 1e-5f);
    int cglob = c0 + 2 * cg + jj;
    if (cglob < C) {
#pragma unroll
      for (int i = 0; i < 4; i++) {
        int d = 4 * dg + i;
        float o = (cacc[i][jj] - mean) * inv * addln_w[d] + addln_b[d];
        out[((size_t)(b * DDIM + d) * MAXR + r) * MAXC + cglob] = o;
      }
    }
  }
}

// ---------------------------------------------------------------------------
extern "C" void kernel_launch(void* const* d_in, const int* in_sizes, int n_in,
                              void* d_out, int out_size, void* d_ws, size_t ws_size,
                              hipStream_t stream) {
  const int*   nr       = (const int*)d_in[0];
  const int*   nc       = (const int*)d_in[1];
  const float* feat     = (const float*)d_in[2];
  const float* boxes    = (const float*)d_in[3];
  const float* proj_w   = (const float*)d_in[4];
  const float* proj_b   = (const float*)d_in[5];
  const float* bbox_w   = (const float*)d_in[6];
  const float* bbox_b   = (const float*)d_in[7];
  const float* bboxln_w = (const float*)d_in[8];
  const float* bboxln_b = (const float*)d_in[9];
  const float* conv_w   = (const float*)d_in[10];
  const float* conv_b   = (const float*)d_in[11];
  const float* addln_w  = (const float*)d_in[12];
  const float* addln_b  = (const float*)d_in[13];
  float* out = (float*)d_out;

  const size_t wbytes = WS_WBYTES;                                  // 1.25 MB
  const size_t tbytes = TF_FLOATS * sizeof(float);                  // 134 MB
  const dim3 grid(MAXC / CELLS, MAXR, BB);

  if (ws_size >= wbytes) {
    unsigned short* pwA_hi = (unsigned short*)d_ws;
    unsigned short* pwA_lo = pwA_hi + PWA_USHORTS;
    unsigned short* cwA_hi = pwA_lo + PWA_USHORTS;
    unsigned short* cwA_lo = cwA_hi + CWA_USHORTS;
    {
      int blocks = (PWA_USHORTS + CWA_USHORTS + 255) / 256;         // 1280
      k_wtrans<<<dim3(blocks), dim3(256), 0, stream>>>(proj_w, conv_w,
                                                       pwA_hi, pwA_lo, cwA_hi, cwA_lo);
    }
    if (ws_size >= wbytes + tbytes) {
      float* tfeat = (float*)(cwA_lo + CWA_USHORTS);
      k_transpose<<<dim3(HW / 32, CIN_ / 32, BB), dim3(256), 0, stream>>>(feat, tfeat);
      k_main_fast<true><<<grid, dim3(256), 0, stream>>>(
          tfeat, boxes, pwA_hi, pwA_lo, cwA_hi, cwA_lo, proj_b,
          bbox_w, bbox_b, bboxln_w, bboxln_b, conv_b, addln_w, addln_b, nr, nc, out);
    } else {
      k_main_fast<false><<<grid, dim3(256), 0, stream>>>(
          feat, boxes, pwA_hi, pwA_lo, cwA_hi, cwA_lo, proj_b,
          bbox_w, bbox_b, bboxln_w, bboxln_b, conv_b, addln_w, addln_b, nr, nc, out);
    }
  } else {
    {
      size_t total = (size_t)BB * DDIM * MAXR * MAXC / 4 + (size_t)BB * MAXR * MAXC;
      int blocks = (int)((total + 255) / 256);
      k_init<<<dim3(blocks), dim3(256), 0, stream>>>(out, nr, nc);
    }
    k_main_safe<<<grid, dim3(256), 0, stream>>>(
        feat, boxes, proj_w, proj_b, bbox_w, bbox_b, bboxln_w, bboxln_b,
        conv_w, conv_b, addln_w, addln_b, nr, nc, out);
  }
}